// Round 6
// baseline (160.622 us; speedup 1.0000x reference)
//
#include <hip/hip_runtime.h>
#include <hip/hip_fp16.h>
#include <stdint.h>

#define BATCH 4096
#define N_IN  512
#define H1    1536
#define H2    1536
#define N_OUT 512
#define FAN   32
#define E0 (H1 * FAN)
#define E1 (H2 * FAN)
#define E2 (N_OUT * FAN)
#define ETOT (E0 + E1 + E2)
#define NNODES (H1 + H2 + N_OUT)   // 3584 non-input nodes
#define MAXDEG 128                 // slot capacity; Poisson(32) max ~54, 128 = guard-free staging

// anti-aliasing row pad (R5: harmless, kept): 520 uint4 = 8320 B = 65 cache lines
#define ROWU4 520
#define ROWH  (ROWU4 * 8)          // halfs per nv row = 4160

// ---- workspace layout (bytes), total 37,763,072 (< 38.7 MB proven safe) ----
#define OFF_EDGES 34078720
#define OFF_CNT   (OFF_EDGES + NNODES * MAXDEG * 8)

// ---------- x [B, N_IN] fp32 -> rows 0..511 of nv (fp16, [node][batch], padded) ----------
__global__ __launch_bounds__(256) void k_transpose_in(const float* __restrict__ x,
                                                      __half* __restrict__ xT) {
    __shared__ float tile[32][33];
    const int tx = threadIdx.x, ty = threadIdx.y;   // 32 x 8
    const int n0 = blockIdx.x * 32;                 // node base
    const int b0 = blockIdx.y * 32;                 // batch base
#pragma unroll
    for (int k = 0; k < 32; k += 8)
        tile[ty + k][tx] = x[(size_t)(b0 + ty + k) * N_IN + (n0 + tx)];
    __syncthreads();
#pragma unroll
    for (int k = 0; k < 32; k += 8)
        xT[(size_t)(n0 + ty + k) * ROWH + (b0 + tx)] = __float2half_rn(tile[tx][ty + k]);
}

// ---------- slotted edge-table fill: one pass, no scan ----------
__global__ __launch_bounds__(256) void k_fill(const int* __restrict__ s0, const int* __restrict__ d0, const float* __restrict__ w0,
                                              const int* __restrict__ s1, const int* __restrict__ d1, const float* __restrict__ w1,
                                              const int* __restrict__ s2, const int* __restrict__ d2, const float* __restrict__ w2,
                                              int* __restrict__ cnt, int2* __restrict__ edges) {
    const int e = blockIdx.x * 256 + threadIdx.x;
    int src, node; float w;
    if (e < E0)           { src = s0[e];          node = d0[e];                w = w0[e]; }
    else if (e < E0 + E1) { int i = e - E0;       src = s1[i]; node = H1 + d1[i];        w = w1[i]; }
    else                  { int i = e - E0 - E1;  src = s2[i]; node = H1 + H2 + d2[i];   w = w2[i]; }
    const int pos = atomicAdd(&cnt[node], 1);
    if (pos < MAXDEG) edges[node * MAXDEG + pos] = make_int2(src, __float_as_int(w));
}

// ---------- level kernel: DMA-ring gather ----------
// R6 experiment: the ONLY delta vs the 145.5us R5 base is the gather return path.
// Requests are identical (same addresses, same count, fully coalesced 1KB/edge),
// but data lands in LDS via global_load_lds (DMA, wave-uniform dest + lane*16)
// instead of the VMEM->VGPR writeback, then is read back with ds_read_b128.
// Per-wave private depth-4 ring, counted s_waitcnt vmcnt(3) (never 0 in steady
// state), sched_barrier(0) fences around each wait (guide rule #18).
// LDS 16KB/block -> still 8 blocks/CU = 32 waves/CU (no occupancy change).
__global__ __launch_bounds__(256, 8)
void k_level(const int2* __restrict__ edges,   // pre-offset: level base * MAXDEG
             const int* __restrict__ cnt,      // pre-offset: level node base
             const uint4* __restrict__ nv,     // ROWU4 uint4 per node row (fp16 x8)
             uint4* __restrict__ outb) {       // pre-offset row base (uint4 units)
    __shared__ uint4 sh[4][4][64];             // [wave][slot][lane] = 16 KB
    const int lane = threadIdx.x & 63;
    const int wv   = threadIdx.x >> 6;
    const int node = __builtin_amdgcn_readfirstlane((blockIdx.y << 2) | wv);
    const int col8 = (blockIdx.x << 6) | lane;  // uint4 index in row, 0..511

    int c = cnt[node];
    c = (c < 0) ? 0 : (c > MAXDEG ? MAXDEG : c);

    float a0 = 0.f, a1 = 0.f, a2 = 0.f, a3 = 0.f, a4 = 0.f, a5 = 0.f, a6 = 0.f, a7 = 0.f;

#define ACC8(q, W) {                                                    \
    const __half2 h0 = *(const __half2*)&(q).x;                         \
    const __half2 h1 = *(const __half2*)&(q).y;                         \
    const __half2 h2 = *(const __half2*)&(q).z;                         \
    const __half2 h3 = *(const __half2*)&(q).w;                         \
    a0 = fmaf(__low2float(h0),  (W), a0);                               \
    a1 = fmaf(__high2float(h0), (W), a1);                               \
    a2 = fmaf(__low2float(h1),  (W), a2);                               \
    a3 = fmaf(__high2float(h1), (W), a3);                               \
    a4 = fmaf(__low2float(h2),  (W), a4);                               \
    a5 = fmaf(__high2float(h2), (W), a5);                               \
    a6 = fmaf(__low2float(h3),  (W), a6);                               \
    a7 = fmaf(__high2float(h3), (W), a7); }

// issue DMA: 64 lanes x 16B contiguous from row SRC into slot K (wave-uniform dest)
#define GLD(K, SRC)                                                                   \
    __builtin_amdgcn_global_load_lds(                                                 \
        (const __attribute__((address_space(1))) void*)(const void*)                  \
            (nv + (size_t)(SRC) * ROWU4 + col8),                                      \
        (__attribute__((address_space(3))) void*)(void*)(&sh[wv][K][0]), 16, 0, 0)

// consume slot K for edge J+K: counted wait (oldest of 4 done), read back, FMA
#define CONS(K, J, WAITSTR) {                                                         \
    asm volatile(WAITSTR ::: "memory");                                               \
    __builtin_amdgcn_sched_barrier(0);                                                \
    const uint4 q = sh[wv][K][lane];                                                  \
    const float w = __int_as_float(__builtin_amdgcn_readlane(my.y, (J) + (K)));       \
    ACC8(q, w);                                                                       \
    __builtin_amdgcn_sched_barrier(0);                                                \
}

#define REISS(K, J) {                                                                 \
    const int s = __builtin_amdgcn_readlane(my.x, (J) + 4 + (K)) & 4095;              \
    GLD(K, s);                                                                        \
}

    const int nfull = ((c > 64) ? 64 : c) & ~3;   // edges handled by the DMA ring

    if (nfull >= 4) {
        // stage this node's first 64 edges into lane registers (always in-bounds)
        const int2 my = edges[(size_t)node * MAXDEG + lane];

        // prologue: 4 DMAs in flight
        {
            const int sa = __builtin_amdgcn_readlane(my.x, 0) & 4095;
            const int sb = __builtin_amdgcn_readlane(my.x, 1) & 4095;
            const int sc = __builtin_amdgcn_readlane(my.x, 2) & 4095;
            const int sd = __builtin_amdgcn_readlane(my.x, 3) & 4095;
            GLD(0, sa); GLD(1, sb); GLD(2, sc); GLD(3, sd);
        }

        int j = 0;
        for (; j + 8 <= nfull; j += 4) {
            CONS(0, j, "s_waitcnt vmcnt(3)") REISS(0, j)
            CONS(1, j, "s_waitcnt vmcnt(3)") REISS(1, j)
            CONS(2, j, "s_waitcnt vmcnt(3)") REISS(2, j)
            CONS(3, j, "s_waitcnt vmcnt(3)") REISS(3, j)
        }
        // epilogue: drain the last 4 (counts decrease to 0)
        CONS(0, j, "s_waitcnt vmcnt(3)")
        CONS(1, j, "s_waitcnt vmcnt(2)")
        CONS(2, j, "s_waitcnt vmcnt(1)")
        CONS(3, j, "s_waitcnt vmcnt(0)")
    }

    // tail: c%4 edges (and the astronomically-rare c>64 overflow) via direct loads
    for (int t = nfull; t < c; ++t) {
        const int2 e = edges[(size_t)node * MAXDEG + t];
        const int   s = e.x & 4095;
        const float w = __int_as_float(e.y);
        const uint4 q = nv[(size_t)s * ROWU4 + col8];
        ACC8(q, w);
    }
#undef REISS
#undef CONS
#undef GLD
#undef ACC8

    a0 = fmaxf(a0, 0.f); a1 = fmaxf(a1, 0.f); a2 = fmaxf(a2, 0.f); a3 = fmaxf(a3, 0.f);
    a4 = fmaxf(a4, 0.f); a5 = fmaxf(a5, 0.f); a6 = fmaxf(a6, 0.f); a7 = fmaxf(a7, 0.f);

    const __half2 h0 = __floats2half2_rn(a0, a1);
    const __half2 h1 = __floats2half2_rn(a2, a3);
    const __half2 h2 = __floats2half2_rn(a4, a5);
    const __half2 h3 = __floats2half2_rn(a6, a7);
    uint4 p;
    p.x = *(const uint32_t*)&h0; p.y = *(const uint32_t*)&h1;
    p.z = *(const uint32_t*)&h2; p.w = *(const uint32_t*)&h3;
    outb[(size_t)node * ROWU4 + col8] = p;
}

// ---------- out^T rows (fp16, padded [N_OUT][ROWH]) -> d_out [B, N_OUT] fp32 ----------
__global__ __launch_bounds__(256) void k_transpose_out(const __half* __restrict__ outh,
                                                       float* __restrict__ out) {
    __shared__ float tile[32][33];
    const int tx = threadIdx.x, ty = threadIdx.y;   // 32 x 8
    const int n0 = blockIdx.x * 32;
    const int b0 = blockIdx.y * 32;
#pragma unroll
    for (int k = 0; k < 32; k += 8)
        tile[ty + k][tx] = __half2float(outh[(size_t)(n0 + ty + k) * ROWH + (b0 + tx)]);
    __syncthreads();
#pragma unroll
    for (int k = 0; k < 32; k += 8)
        out[(size_t)(b0 + ty + k) * N_OUT + (n0 + tx)] = tile[tx][ty + k];
}

extern "C" void kernel_launch(void* const* d_in, const int* in_sizes, int n_in,
                              void* d_out, int out_size, void* d_ws, size_t ws_size,
                              hipStream_t stream) {
    const float* x  = (const float*)d_in[0];
    const int* s0   = (const int*)d_in[1];
    const int* dd0  = (const int*)d_in[2];
    const float* w0 = (const float*)d_in[3];
    const int* s1   = (const int*)d_in[4];
    const int* dd1  = (const int*)d_in[5];
    const float* w1 = (const float*)d_in[6];
    const int* s2   = (const int*)d_in[7];
    const int* dd2  = (const int*)d_in[8];
    const float* w2 = (const float*)d_in[9];

    char* ws        = (char*)d_ws;
    uint4*    nv4   = (uint4*)ws;                    // fp16 node rows, ROWU4 uint4/row
    int2*     edges = (int2*)(ws + OFF_EDGES);
    int*      cnt   = (int*)(ws + OFF_CNT);

    // slotted edge build: memset + one massively-parallel fill (no scan)
    hipMemsetAsync(cnt, 0, NNODES * sizeof(int), stream);
    k_fill<<<ETOT / 256, 256, 0, stream>>>(s0, dd0, w0, s1, dd1, w1, s2, dd2, w2, cnt, edges);

    // x -> fp16 transposed node-value rows 0..511
    k_transpose_in<<<dim3(N_IN / 32, BATCH / 32), dim3(32, 8), 0, stream>>>(x, (__half*)ws);

    // levels: grid (8 col-tiles, H/4), 256 threads = 4 waves = 4 nodes
    k_level<<<dim3(8, H1 / 4), 256, 0, stream>>>(edges, cnt, nv4,
                                                 nv4 + (size_t)N_IN * ROWU4);
    k_level<<<dim3(8, H2 / 4), 256, 0, stream>>>(edges + (size_t)H1 * MAXDEG, cnt + H1, nv4,
                                                 nv4 + (size_t)(N_IN + H1) * ROWU4);
    k_level<<<dim3(8, N_OUT / 4), 256, 0, stream>>>(edges + (size_t)(H1 + H2) * MAXDEG, cnt + H1 + H2, nv4,
                                                    nv4 + (size_t)(N_IN + H1 + H2) * ROWU4);

    // out^T (fp16) -> d_out [B, N_OUT] fp32
    k_transpose_out<<<dim3(N_OUT / 32, BATCH / 32), dim3(32, 8), 0, stream>>>(
        (const __half*)(ws + (size_t)(N_IN + H1 + H2) * ROWH * 2), (float*)d_out);
}